// Round 12
// baseline (469.427 us; speedup 1.0000x reference)
//
#include <hip/hip_runtime.h>
#include <math.h>

// Problem constants: B=512, C=50000, D=256.
#define D_DIM 256
#define TM 128
#define TN 128
#define BK 32     // K-tile depth (bf16); 8 K-iterations
#define NBP 392   // padded partial stride (NB=391)
#define CBPR 7    // compress blocks per row (7*4 waves*2048 cols = 57344 >= 50000)
#define CBLKS (CBPR * 512)   // 3584 compress-role blocks

typedef __attribute__((ext_vector_type(8))) short short8;
typedef __attribute__((ext_vector_type(4))) float floatx4;
typedef unsigned long long u64;

__device__ __forceinline__ unsigned short f2bf(float f) {
    unsigned int u = __float_as_uint(f);
    u += 0x7FFFu + ((u >> 16) & 1u);   // round-to-nearest-even
    return (unsigned short)(u >> 16);
}

// async global->LDS 16B: lane l's 16B lands at ldsbase + l*16 (wave-uniform base)
__device__ __forceinline__ void gload16(const void* g, void* lds) {
    __builtin_amdgcn_global_load_lds(
        (const __attribute__((address_space(1))) unsigned int*)g,
        (__attribute__((address_space(3))) unsigned int*)lds, 16, 0, 0);
}

// ---- kernel 1 (R12): rows-only prep -- loadedmask, zero scratch, normalize -> bf16.
// (R8-verified code; ~44us implied. Compress moved into kernel 2 for overlap.)
__global__ __launch_bounds__(256) void prep_rows(
    const float* __restrict__ V, const float* __restrict__ T,
    const int* __restrict__ ids,
    u64* __restrict__ loadedmask,
    unsigned short* __restrict__ Vb, unsigned short* __restrict__ Tb,
    float* __restrict__ gaccum, unsigned int* __restrict__ gcount,
    unsigned int* __restrict__ cdone,
    int B, int C, int n_loaded, int WPR) {
    const int tid  = threadIdx.x;
    const int lane = tid & 63;
    int ptid = blockIdx.x * 256 + tid;
    if (ptid == 0) { *gcount = 0u; *gaccum = 0.f; *cdone = 0u; }
    if (ptid < WPR) {
        int base = ptid << 6;
        int lo = 0, hi = n_loaded;
        while (lo < hi) { int mid = (lo + hi) >> 1; if (ids[mid] < base) lo = mid + 1; else hi = mid; }
        u64 m = 0;
        for (int i = lo; i < n_loaded; ++i) {
            int v = ids[i]; if (v >= base + 64) break;
            m |= 1ull << (v - base);
        }
        loadedmask[ptid] = m;
    }
    int wave = ptid >> 6;
    if (wave >= B + C) return;   // whole wave uniform
    bool isV = wave < B;
    const float* src = isV ? (V + (size_t)wave * D_DIM)
                           : (T + (size_t)(wave - B) * D_DIM);
    float4 x = ((const float4*)src)[lane];
    float ss = x.x * x.x + x.y * x.y + x.z * x.z + x.w * x.w;
    #pragma unroll
    for (int off = 32; off > 0; off >>= 1) ss += __shfl_xor(ss, off);
    float nrm = sqrtf(ss);
    float s = isV ? (1.0f / nrm) : (1.0f / (1e-6f + nrm));   // eps on text norms only
    ushort4 o;
    o.x = f2bf(x.x * s); o.y = f2bf(x.y * s);
    o.z = f2bf(x.z * s); o.w = f2bf(x.w * s);
    unsigned short* dst = isV ? (Vb + (size_t)wave * D_DIM)
                              : (Tb + (size_t)(wave - B) * D_DIM);
    ((ushort4*)dst)[lane] = o;
}

// ---- kernel 2 (R12): compress role (bid<CBLKS, dispatches FIRST) + gemm role --------
// gemm's K-loop needs only Vb/Tb (ready: launch boundary); posmask is needed only in
// the epilogue, so compress streams labels WHILE gemm mainloops run. Epilogue
// soft-syncs on cdone (release fence on writers / acquire fence on reader -- the
// R10-verified visibility pattern). Liveness does NOT depend on dispatch order:
// bounded spin, then fallback recomputes the lane's mask from labels (R8-verified
// path, same bits, just slower). reduce_rows stays standalone (R10 lesson: a 4-block
// merged reduce serializes 128-blocks' work onto 4 = +130us tail).
__global__ __launch_bounds__(256) void compress_gemm(
    const unsigned short* __restrict__ Vb, const unsigned short* __restrict__ Tb,
    const int* __restrict__ label, const u64* __restrict__ loadedmask,
    u64* __restrict__ posmask, unsigned int* __restrict__ cdone,
    float* __restrict__ denomP, float* __restrict__ posP, int C, int WPR) {
    __shared__ unsigned short As[2][TM * BK];   // 2 x 8 KB double buffer
    __shared__ unsigned short Bs[2][TN * BK];   // 2 x 8 KB
    __shared__ float sDen[TM], sPos[TM];
    __shared__ int sReady;

    const int bid  = blockIdx.x;
    const int tid  = threadIdx.x;
    const int lane = tid & 63;

    if (bid < CBLKS) {   // ---- compress role (R5-exact body, barrier-safe guard)
        int row = bid / CBPR;
        int sub = bid - row * CBPR;
        int wl  = tid >> 6;
        int w0col = (sub * 4 + wl) * 2048;     // this wave's 2048-col window
        if (w0col < C) {
            const int* lp = label + (size_t)row * C;
            int4 lo[4], hi[4];
            #pragma unroll
            for (int r = 0; r < 4; ++r) {      // 8 x 16B loads in flight
                int c0 = w0col + r * 512 + lane * 8;
                if (c0 < C) {                  // C%8==0: full 8-col chunk valid
                    lo[r] = *(const int4*)(lp + c0);
                    hi[r] = *(const int4*)(lp + c0 + 4);
                } else {
                    lo[r] = make_int4(0, 0, 0, 0);
                    hi[r] = make_int4(0, 0, 0, 0);
                }
            }
            #pragma unroll
            for (int r = 0; r < 4; ++r) {
                unsigned int by =
                    (lo[r].x ? 1u : 0u) | (lo[r].y ? 2u : 0u) |
                    (lo[r].z ? 4u : 0u) | (lo[r].w ? 8u : 0u) |
                    (hi[r].x ? 16u : 0u) | (hi[r].y ? 32u : 0u) |
                    (hi[r].z ? 64u : 0u) | (hi[r].w ? 128u : 0u);
                u64 wv = (u64)by << (8 * (lane & 7));
                wv |= __shfl_xor(wv, 1);       // OR-butterfly across 8-lane group
                wv |= __shfl_xor(wv, 2);
                wv |= __shfl_xor(wv, 4);
                if ((lane & 7) == 0) {
                    int wc = ((w0col + r * 512) >> 6) + (lane >> 3);
                    if (wc < WPR) posmask[(size_t)row * WPR + wc] = wv;
                }
            }
        }
        __syncthreads();
        if (tid == 0) { __threadfence(); atomicAdd(cdone, 1u); }   // release+publish
        return;
    }

    // ---- gemm role (R5-exact mainloop) ------------------------------------------
    const int g  = bid - CBLKS;
    const int m0 = (g & 3) * TM;        // m fastest: 4 blocks share one T-tile
    const int n0 = (g >> 2) * TN;
    const int w  = tid >> 6;

    if (tid < TM) { sDen[tid] = 0.f; sPos[tid] = 0.f; }

    const int sra = lane >> 2;          // row within 16-row group
    const int kc  = (lane & 3) * 8;     // 16B k-chunk
    int ga  = m0 + w * 32 + sra;
    int gb0 = n0 + w * 32 + sra;
    int gb1 = gb0 + 16;
    if (gb0 >= C) gb0 = C - 1;          // OOB rows: valid address, masked in epilogue
    if (gb1 >= C) gb1 = C - 1;
    const unsigned short* gA0 = Vb + (size_t)ga * D_DIM + kc;
    const unsigned short* gA1 = gA0 + (size_t)16 * D_DIM;
    const unsigned short* gB0 = Tb + (size_t)gb0 * D_DIM + kc;
    const unsigned short* gB1 = Tb + (size_t)gb1 * D_DIM + kc;
    const int lofsA = w * 32 * BK;      // wave-uniform LDS offsets (elements)
    const int lofsB = w * 32 * BK;

    const int wm = (w >> 1) * 64;
    const int wn = (w & 1) * 64;
    const int fr = lane & 15;
    const int quad = lane >> 4;

    floatx4 acc[4][4];
    #pragma unroll
    for (int mi = 0; mi < 4; mi++)
        #pragma unroll
        for (int ni = 0; ni < 4; ni++) acc[mi][ni] = (floatx4)0.f;

    gload16(gA0, &As[0][lofsA]);
    gload16(gA1, &As[0][lofsA + 16 * BK]);
    gload16(gB0, &Bs[0][lofsB]);
    gload16(gB1, &Bs[0][lofsB + 16 * BK]);
    __syncthreads();

    #pragma unroll
    for (int kt = 0; kt < D_DIM / BK; ++kt) {
        const int cur = kt & 1;          // compile-time under full unroll
        if (kt < D_DIM / BK - 1) {       // stage NEXT tile into the other buffer
            const int kb = (kt + 1) * BK;
            gload16(gA0 + kb, &As[cur ^ 1][lofsA]);
            gload16(gA1 + kb, &As[cur ^ 1][lofsA + 16 * BK]);
            gload16(gB0 + kb, &Bs[cur ^ 1][lofsB]);
            gload16(gB1 + kb, &Bs[cur ^ 1][lofsB + 16 * BK]);
        }
        short8 af[4], bf[4];
        #pragma unroll
        for (int mi = 0; mi < 4; mi++)
            af[mi] = *(const short8*)&As[cur][(wm + mi * 16 + fr) * BK + quad * 8];
        #pragma unroll
        for (int ni = 0; ni < 4; ni++)
            bf[ni] = *(const short8*)&Bs[cur][(wn + ni * 16 + fr) * BK + quad * 8];
        #pragma unroll
        for (int mi = 0; mi < 4; mi++)
            #pragma unroll
            for (int ni = 0; ni < 4; ni++)
                acc[mi][ni] = __builtin_amdgcn_mfma_f32_16x16x32_bf16(
                    af[mi], bf[ni], acc[mi][ni], 0, 0, 0);
        __syncthreads();                 // drains this step's stage; swap point
    }

    // ---- soft-sync: posmask ready? (normal case: yes on first poll) --------------
    if (tid == 0) {
        int ready = 0;
        for (int it = 0; it < 50000; ++it) {
            if (atomicAdd(cdone, 0u) >= (unsigned int)CBLKS) { ready = 1; break; }
        }
        if (ready) __threadfence();      // acquire: drop stale L1/L2
        sReady = ready;
    }
    __syncthreads();

    // per-lane raw mask for row m0+wm+lane over this wave's 64-col word
    const int wcol = (n0 + wn) >> 6;
    const u64 loadedw = loadedmask[wcol];
    u64 praw;
    if (sReady) {
        praw = posmask[(size_t)(m0 + wm + lane) * WPR + wcol];
    } else {   // fallback: recompute from labels (R8-verified; same bits)
        const int* lp = label + (size_t)(m0 + wm + lane) * C;
        const int nBase = n0 + wn;
        praw = 0;
        #pragma unroll
        for (int k = 0; k < 16; ++k) {
            const int col0 = nBase + 4 * k;
            unsigned int nib = 0;
            if (col0 + 3 < C) {
                int4 v = *(const int4*)(lp + col0);
                nib = (v.x ? 1u : 0u) | (v.y ? 2u : 0u) | (v.z ? 4u : 0u) | (v.w ? 8u : 0u);
            } else {
                if (col0 + 0 < C && lp[col0 + 0]) nib |= 1u;
                if (col0 + 1 < C && lp[col0 + 1]) nib |= 2u;
                if (col0 + 2 < C && lp[col0 + 2]) nib |= 4u;
                if (col0 + 3 < C && lp[col0 + 3]) nib |= 8u;
            }
            praw |= (u64)nib << (4 * k);
        }
    }

    // ---- epilogue (R8-verified shfl form): row = quad*4 + reg, col = lane&15 -----
    #pragma unroll
    for (int mi = 0; mi < 4; mi++) {
        #pragma unroll
        for (int i = 0; i < 4; i++) {
            const int rloc = mi * 16 + quad * 4 + i;
            const int mloc = wm + rloc;
            const u64 pr = __shfl(praw, rloc);   // row rloc's raw mask
            const u64 posw = pr & loadedw;
            const u64 negw = loadedw & ~pr;
            float den = 0.f, pos = 0.f;
            #pragma unroll
            for (int ni = 0; ni < 4; ni++) {
                const float s = acc[mi][ni][i];
                const int bit = ni * 16 + fr;
                if ((negw >> bit) & 1) den += __expf(s);
                if ((posw >> bit) & 1) pos += s;
            }
            #pragma unroll
            for (int off = 8; off >= 1; off >>= 1) {   // reduce 16-lane quad row
                den += __shfl_xor(den, off);
                pos += __shfl_xor(pos, off);
            }
            if (fr == 0) {
                if (den != 0.f) atomicAdd(&sDen[mloc], den);
                if (pos != 0.f) atomicAdd(&sPos[mloc], pos);
            }
        }
    }
    __syncthreads();
    if (tid < TM) {   // row-major partials: [row][n-block] for coalesced reduce
        denomP[(size_t)(m0 + tid) * NBP + (g >> 2)] = sDen[tid];
        posP[(size_t)(m0 + tid) * NBP + (g >> 2)]   = sPos[tid];
    }
}

// ---- kernel 3: reduce rows + last-block computes the final mean (R5-exact) ----------
__global__ void reduce_rows(const float* __restrict__ denomP, const float* __restrict__ posP,
                            const u64* __restrict__ posmask, const u64* __restrict__ loadedmask,
                            float* __restrict__ gaccum, unsigned int* __restrict__ gcount,
                            float* __restrict__ out, int B, int NB, int WPR) {
    __shared__ float bsum[4];
    int wv   = threadIdx.x >> 6;
    int row  = blockIdx.x * 4 + wv;
    int lane = threadIdx.x & 63;
    float den = 0.f, pos = 0.f;
    int cnt = 0;
    if (row < B) {
        for (int bn = lane; bn < NB; bn += 64) {   // contiguous within row: coalesced
            den += denomP[(size_t)row * NBP + bn];
            pos += posP[(size_t)row * NBP + bn];
        }
        for (int j = lane; j < WPR; j += 64)
            cnt += __popcll(posmask[(size_t)row * WPR + j] & loadedmask[j]);
        #pragma unroll
        for (int off = 32; off > 0; off >>= 1) {
            den += __shfl_xor(den, off);
            pos += __shfl_xor(pos, off);
            cnt += __shfl_xor(cnt, off);
        }
    }
    if (lane == 0) bsum[wv] = (row < B) ? (logf(den) - pos / (float)cnt) : 0.f;
    __syncthreads();
    if (threadIdx.x == 0) {
        float s = bsum[0] + bsum[1] + bsum[2] + bsum[3];
        atomicAdd(gaccum, s);            // 128 ops total: contention negligible
        __threadfence();
        unsigned int old = atomicAdd(gcount, 1u);
        if (old == gridDim.x - 1) {      // last block: all adds complete & visible
            float tot = atomicAdd(gaccum, 0.0f);   // atomic read-back
            out[0] = tot / (float)B;
        }
    }
}

extern "C" void kernel_launch(void* const* d_in, const int* in_sizes, int n_in,
                              void* d_out, int out_size, void* d_ws, size_t ws_size,
                              hipStream_t stream) {
    const float* V     = (const float*)d_in[0];
    const float* T     = (const float*)d_in[1];
    const int*   label = (const int*)d_in[2];
    const int*   ids   = (const int*)d_in[3];
    int B = in_sizes[0] / D_DIM;   // 512
    int C = in_sizes[1] / D_DIM;   // 50000
    int n_loaded = in_sizes[3];    // 40000
    int WPR = (C + 63) >> 6;       // mask words per row (782)
    int NB  = (C + TN - 1) / TN;   // n-blocks (391)

    // ws layout (bytes):
    //   0        : gaccum [1 f], gcount [1 u32] @8, cdone [1 u32] @16
    //   2048     : loadedmask [782 u64]             (ends 8304; pad to 8320)
    //   8320     : posmask [512*782 u64]            (3,203,072 -> ends 3,211,392)
    //   3211392  : Vb [512*256 bf16]                (262,144 -> ends 3,473,536)
    //   3473536  : Tb [50000*256 bf16]              (25.6 MB -> ends 29,073,536)
    //   29073536 : denomP [512*NBP f]               (802,816 -> ends 29,876,352)
    //   29876352 : posP                             (ends 30,679,168)
    char* ws = (char*)d_ws;
    float*        gaccum = (float*)(ws + 0);
    unsigned int* gcount = (unsigned int*)(ws + 8);
    unsigned int* cdone  = (unsigned int*)(ws + 16);
    u64*   loadedmask = (u64*)(ws + 2048);
    u64*   posmask    = (u64*)(ws + 8320);
    unsigned short* Vb = (unsigned short*)(ws + 3211392);
    unsigned short* Tb = (unsigned short*)(ws + 3473536);
    float* denomP  = (float*)(ws + 29073536);
    float* posP    = (float*)(ws + 29876352);

    int prep_blocks = ((B + C) * 64 + 255) / 256;    // 12628
    prep_rows<<<prep_blocks, 256, 0, stream>>>(
        V, T, ids, loadedmask, Vb, Tb, gaccum, gcount, cdone,
        B, C, n_loaded, WPR);

    int gemm_blocks = (B / TM) * NB;   // 1564 (m fastest in linearization)
    compress_gemm<<<CBLKS + gemm_blocks, 256, 0, stream>>>(
        Vb, Tb, label, loadedmask, posmask, cdone, denomP, posP, C, WPR);

    reduce_rows<<<(B + 3) / 4, 256, 0, stream>>>(denomP, posP, posmask, loadedmask,
                                                 gaccum, gcount, (float*)d_out, B, NB, WPR);
}

// Round 13
// 254.626 us; speedup vs baseline: 1.8436x; 1.8436x over previous
//
#include <hip/hip_runtime.h>
#include <math.h>

// Problem constants: B=512, C=50000, D=256.
#define D_DIM 256
#define TM 128
#define TN 128
#define BK 32     // K-tile depth (bf16); 8 K-iterations
#define NBP 392   // padded partial stride (NB=391)
#define CBPR 7    // compress blocks per row (7*4 waves*2048 cols = 57344 >= 50000)
#define CBLKS (CBPR * 512)   // 3584 compress-role blocks

typedef __attribute__((ext_vector_type(8))) short short8;
typedef __attribute__((ext_vector_type(4))) float floatx4;
typedef __attribute__((ext_vector_type(4))) int intx4;
typedef unsigned long long u64;

__device__ __forceinline__ unsigned short f2bf(float f) {
    unsigned int u = __float_as_uint(f);
    u += 0x7FFFu + ((u >> 16) & 1u);   // round-to-nearest-even
    return (unsigned short)(u >> 16);
}

// async global->LDS 16B: lane l's 16B lands at ldsbase + l*16 (wave-uniform base)
__device__ __forceinline__ void gload16(const void* g, void* lds) {
    __builtin_amdgcn_global_load_lds(
        (const __attribute__((address_space(1))) unsigned int*)g,
        (__attribute__((address_space(3))) unsigned int*)lds, 16, 0, 0);
}

// ---- kernel 1: fused label-compress (role A) + norms/bf16-convert/loadedmask (role B)
// R5-exact structure (best measured 263.16; R10 merge / R12 intra-grid overlap both
// regressed badly and are reverted). R13 delta: NONTEMPORAL loads on the two
// read-once streams (labels 102MB, V/T 51MB) so they stop evicting Vb/Tb -- the only
// data with reuse (gemm re-reads Tb ~4x through L2/L3) -- from the caches.
__global__ __launch_bounds__(256) void prep_compress(
    const float* __restrict__ V, const float* __restrict__ T,
    const int* __restrict__ label, const int* __restrict__ ids,
    u64* __restrict__ loadedmask, u64* __restrict__ posmask,
    unsigned short* __restrict__ Vb, unsigned short* __restrict__ Tb,
    float* __restrict__ gaccum, unsigned int* __restrict__ gcount,
    int B, int C, int n_loaded, int WPR) {
    const int bid = blockIdx.x;
    const int tid = threadIdx.x;
    const int lane = tid & 63;

    if (bid < CBLKS) {   // ---- compress role: 102 MB label stream -> 3.2 MB raw posmask
        int row = bid / CBPR;
        int sub = bid - row * CBPR;
        int wl  = tid >> 6;
        int w0col = (sub * 4 + wl) * 2048;     // this wave's 2048-col window
        if (w0col >= C) return;
        const int* lp = label + (size_t)row * C;
        intx4 lo[4], hi[4];
        #pragma unroll
        for (int r = 0; r < 4; ++r) {          // 8 x 16B nt loads in flight
            int c0 = w0col + r * 512 + lane * 8;
            if (c0 < C) {                      // C%8==0: full 8-col chunk valid
                lo[r] = __builtin_nontemporal_load((const intx4*)(lp + c0));
                hi[r] = __builtin_nontemporal_load((const intx4*)(lp + c0 + 4));
            } else {
                lo[r] = (intx4)0;
                hi[r] = (intx4)0;
            }
        }
        #pragma unroll
        for (int r = 0; r < 4; ++r) {
            unsigned int by =
                (lo[r][0] ? 1u : 0u) | (lo[r][1] ? 2u : 0u) |
                (lo[r][2] ? 4u : 0u) | (lo[r][3] ? 8u : 0u) |
                (hi[r][0] ? 16u : 0u) | (hi[r][1] ? 32u : 0u) |
                (hi[r][2] ? 64u : 0u) | (hi[r][3] ? 128u : 0u);
            u64 wv = (u64)by << (8 * (lane & 7));
            wv |= __shfl_xor(wv, 1);           // OR-butterfly across 8-lane group
            wv |= __shfl_xor(wv, 2);
            wv |= __shfl_xor(wv, 4);
            if ((lane & 7) == 0) {
                int wc = ((w0col + r * 512) >> 6) + (lane >> 3);
                if (wc < WPR) posmask[(size_t)row * WPR + wc] = wv;
            }
        }
        return;
    }

    // ---- prep role: loadedmask (binary search over sorted ids) + normalize -> bf16
    int ptid = (bid - CBLKS) * 256 + tid;
    if (ptid == 0) { *gcount = 0u; *gaccum = 0.f; }   // zero reduce scratch each call
    if (ptid < WPR) {
        int base = ptid << 6;
        int lo = 0, hi = n_loaded;
        while (lo < hi) { int mid = (lo + hi) >> 1; if (ids[mid] < base) lo = mid + 1; else hi = mid; }
        u64 m = 0;
        for (int i = lo; i < n_loaded; ++i) {
            int v = ids[i]; if (v >= base + 64) break;
            m |= 1ull << (v - base);
        }
        loadedmask[ptid] = m;
    }
    int wave = ptid >> 6;
    if (wave >= B + C) return;   // whole wave uniform
    bool isV = wave < B;
    const float* src = isV ? (V + (size_t)wave * D_DIM)
                           : (T + (size_t)(wave - B) * D_DIM);
    floatx4 x = __builtin_nontemporal_load(((const floatx4*)src) + lane);
    float ss = x[0] * x[0] + x[1] * x[1] + x[2] * x[2] + x[3] * x[3];
    #pragma unroll
    for (int off = 32; off > 0; off >>= 1) ss += __shfl_xor(ss, off);
    float nrm = sqrtf(ss);
    float s = isV ? (1.0f / nrm) : (1.0f / (1e-6f + nrm));   // eps on text norms only
    ushort4 o;
    o.x = f2bf(x[0] * s); o.y = f2bf(x[1] * s);
    o.z = f2bf(x[2] * s); o.w = f2bf(x[3] * s);
    unsigned short* dst = isV ? (Vb + (size_t)wave * D_DIM)
                              : (Tb + (size_t)(wave - B) * D_DIM);
    ((ushort4*)dst)[lane] = o;   // cached store: Vb/Tb are re-read by gemm
}

// ---- kernel 2: bf16 MFMA S-tile + raw-posmask epilogue (R5-exact) -------------------
__global__ __launch_bounds__(256) void gemm_fused(
    const unsigned short* __restrict__ Vb, const unsigned short* __restrict__ Tb,
    const u64* __restrict__ posmask, const u64* __restrict__ loadedmask,
    float* __restrict__ denomP, float* __restrict__ posP, int C, int WPR) {
    __shared__ unsigned short As[2][TM * BK];   // 2 x 8 KB double buffer
    __shared__ unsigned short Bs[2][TN * BK];   // 2 x 8 KB
    __shared__ float sDen[TM], sPos[TM];

    const int tid  = threadIdx.x;
    const int lane = tid & 63;
    const int w    = tid >> 6;
    const int m0 = blockIdx.x * TM;
    const int n0 = blockIdx.y * TN;

    if (tid < TM) { sDen[tid] = 0.f; sPos[tid] = 0.f; }

    // ---- async-staging addresses: wave w covers tile rows [w*32, w*32+32)
    const int sra = lane >> 2;          // row within 16-row group
    const int kc  = (lane & 3) * 8;     // 16B k-chunk
    int ga  = m0 + w * 32 + sra;
    int gb0 = n0 + w * 32 + sra;
    int gb1 = gb0 + 16;
    if (gb0 >= C) gb0 = C - 1;          // OOB rows: valid address, masked in epilogue
    if (gb1 >= C) gb1 = C - 1;
    const unsigned short* gA0 = Vb + (size_t)ga * D_DIM + kc;
    const unsigned short* gA1 = gA0 + (size_t)16 * D_DIM;
    const unsigned short* gB0 = Tb + (size_t)gb0 * D_DIM + kc;
    const unsigned short* gB1 = Tb + (size_t)gb1 * D_DIM + kc;
    const int lofsA = w * 32 * BK;      // wave-uniform LDS offsets (elements)
    const int lofsB = w * 32 * BK;

    // ---- compute mapping: 2x2 waves, each 64x64 via 4x4 frags of 16x16x32
    const int wm = (w >> 1) * 64;
    const int wn = (w & 1) * 64;
    const int fr = lane & 15;
    const int quad = lane >> 4;

    floatx4 acc[4][4];
    #pragma unroll
    for (int mi = 0; mi < 4; mi++)
        #pragma unroll
        for (int ni = 0; ni < 4; ni++) acc[mi][ni] = (floatx4)0.f;

    // prologue: stage tile 0 into buffer 0, drain, barrier
    gload16(gA0, &As[0][lofsA]);
    gload16(gA1, &As[0][lofsA + 16 * BK]);
    gload16(gB0, &Bs[0][lofsB]);
    gload16(gB1, &Bs[0][lofsB + 16 * BK]);
    __syncthreads();

    #pragma unroll
    for (int kt = 0; kt < D_DIM / BK; ++kt) {
        const int cur = kt & 1;          // compile-time under full unroll
        if (kt < D_DIM / BK - 1) {       // stage NEXT tile into the other buffer
            const int kb = (kt + 1) * BK;
            gload16(gA0 + kb, &As[cur ^ 1][lofsA]);
            gload16(gA1 + kb, &As[cur ^ 1][lofsA + 16 * BK]);
            gload16(gB0 + kb, &Bs[cur ^ 1][lofsB]);
            gload16(gB1 + kb, &Bs[cur ^ 1][lofsB + 16 * BK]);
        }
        short8 af[4], bf[4];
        #pragma unroll
        for (int mi = 0; mi < 4; mi++)
            af[mi] = *(const short8*)&As[cur][(wm + mi * 16 + fr) * BK + quad * 8];
        #pragma unroll
        for (int ni = 0; ni < 4; ni++)
            bf[ni] = *(const short8*)&Bs[cur][(wn + ni * 16 + fr) * BK + quad * 8];
        #pragma unroll
        for (int mi = 0; mi < 4; mi++)
            #pragma unroll
            for (int ni = 0; ni < 4; ni++)
                acc[mi][ni] = __builtin_amdgcn_mfma_f32_16x16x32_bf16(
                    af[mi], bf[ni], acc[mi][ni], 0, 0, 0);
        __syncthreads();                 // drains this step's stage; swap point
    }

    // ---- epilogue: D layout row = quad*4 + reg, col = lane&15 per 16x16 frag.
    const int wcol = (n0 + wn) >> 6;          // this wave's 64-col mask word
    const u64 loadedw = loadedmask[wcol];
    #pragma unroll
    for (int mi = 0; mi < 4; mi++) {
        #pragma unroll
        for (int i = 0; i < 4; i++) {
            const int mloc = wm + mi * 16 + quad * 4 + i;
            const u64 praw = posmask[(size_t)(m0 + mloc) * WPR + wcol];  // L2/L3-hit
            const u64 posw = praw & loadedw;
            const u64 negw = loadedw & ~praw;
            float den = 0.f, pos = 0.f;
            #pragma unroll
            for (int ni = 0; ni < 4; ni++) {
                const float s = acc[mi][ni][i];
                const int bit = ni * 16 + fr;
                if ((negw >> bit) & 1) den += __expf(s);
                if ((posw >> bit) & 1) pos += s;
            }
            #pragma unroll
            for (int off = 8; off >= 1; off >>= 1) {   // reduce 16-lane quad row
                den += __shfl_xor(den, off);
                pos += __shfl_xor(pos, off);
            }
            if (fr == 0) {
                if (den != 0.f) atomicAdd(&sDen[mloc], den);
                if (pos != 0.f) atomicAdd(&sPos[mloc], pos);
            }
        }
    }
    __syncthreads();
    if (tid < TM) {   // row-major partials: [row][n-block] for coalesced reduce
        denomP[(size_t)(m0 + tid) * NBP + blockIdx.y] = sDen[tid];
        posP[(size_t)(m0 + tid) * NBP + blockIdx.y]   = sPos[tid];
    }
}

// ---- kernel 3: reduce rows + last-block computes the final mean (R5-exact) ----------
__global__ void reduce_rows(const float* __restrict__ denomP, const float* __restrict__ posP,
                            const u64* __restrict__ posmask, const u64* __restrict__ loadedmask,
                            float* __restrict__ gaccum, unsigned int* __restrict__ gcount,
                            float* __restrict__ out, int B, int NB, int WPR) {
    __shared__ float bsum[4];
    int wv   = threadIdx.x >> 6;
    int row  = blockIdx.x * 4 + wv;
    int lane = threadIdx.x & 63;
    float den = 0.f, pos = 0.f;
    int cnt = 0;
    if (row < B) {
        for (int bn = lane; bn < NB; bn += 64) {   // contiguous within row: coalesced
            den += denomP[(size_t)row * NBP + bn];
            pos += posP[(size_t)row * NBP + bn];
        }
        for (int j = lane; j < WPR; j += 64)
            cnt += __popcll(posmask[(size_t)row * WPR + j] & loadedmask[j]);
        #pragma unroll
        for (int off = 32; off > 0; off >>= 1) {
            den += __shfl_xor(den, off);
            pos += __shfl_xor(pos, off);
            cnt += __shfl_xor(cnt, off);
        }
    }
    if (lane == 0) bsum[wv] = (row < B) ? (logf(den) - pos / (float)cnt) : 0.f;
    __syncthreads();
    if (threadIdx.x == 0) {
        float s = bsum[0] + bsum[1] + bsum[2] + bsum[3];
        atomicAdd(gaccum, s);            // 128 ops total: contention negligible
        __threadfence();
        unsigned int old = atomicAdd(gcount, 1u);
        if (old == gridDim.x - 1) {      // last block: all adds complete & visible
            float tot = atomicAdd(gaccum, 0.0f);   // atomic read-back
            out[0] = tot / (float)B;
        }
    }
}

extern "C" void kernel_launch(void* const* d_in, const int* in_sizes, int n_in,
                              void* d_out, int out_size, void* d_ws, size_t ws_size,
                              hipStream_t stream) {
    const float* V     = (const float*)d_in[0];
    const float* T     = (const float*)d_in[1];
    const int*   label = (const int*)d_in[2];
    const int*   ids   = (const int*)d_in[3];
    int B = in_sizes[0] / D_DIM;   // 512
    int C = in_sizes[1] / D_DIM;   // 50000
    int n_loaded = in_sizes[3];    // 40000
    int WPR = (C + 63) >> 6;       // mask words per row (782)
    int NB  = (C + TN - 1) / TN;   // n-blocks (391)

    // ws layout (bytes):
    //   0        : gaccum [1 f], gcount [1 u32]     (pad to 2048)
    //   2048     : loadedmask [782 u64]             (ends 8304; pad to 8320)
    //   8320     : posmask [512*782 u64]            (3,203,072 -> ends 3,211,392)
    //   3211392  : Vb [512*256 bf16]                (262,144 -> ends 3,473,536)
    //   3473536  : Tb [50000*256 bf16]              (25.6 MB -> ends 29,073,536)
    //   29073536 : denomP [512*NBP f]               (802,816 -> ends 29,876,352)
    //   29876352 : posP                             (ends 30,679,168)
    char* ws = (char*)d_ws;
    float*        gaccum = (float*)(ws + 0);
    unsigned int* gcount = (unsigned int*)(ws + 8);
    u64*   loadedmask = (u64*)(ws + 2048);
    u64*   posmask    = (u64*)(ws + 8320);
    unsigned short* Vb = (unsigned short*)(ws + 3211392);
    unsigned short* Tb = (unsigned short*)(ws + 3473536);
    float* denomP  = (float*)(ws + 29073536);
    float* posP    = (float*)(ws + 29876352);

    int prep_blocks = ((B + C) * 64 + 255) / 256;    // 12628
    prep_compress<<<CBLKS + prep_blocks, 256, 0, stream>>>(
        V, T, label, ids, loadedmask, posmask, Vb, Tb, gaccum, gcount,
        B, C, n_loaded, WPR);

    dim3 grid(B / TM, NB);   // m fastest: 4 blocks share one T-tile
    gemm_fused<<<grid, 256, 0, stream>>>(Vb, Tb, posmask, loadedmask,
                                         denomP, posP, C, WPR);

    reduce_rows<<<(B + 3) / 4, 256, 0, stream>>>(denomP, posP, posmask, loadedmask,
                                                 gaccum, gcount, (float*)d_out, B, NB, WPR);
}

// Round 15
// 249.559 us; speedup vs baseline: 1.8810x; 1.0203x over previous
//
#include <hip/hip_runtime.h>
#include <math.h>

// Problem constants: B=512, C=50000, D=256.
#define D_DIM 256
#define TM 128
#define TN 128
#define BK 32     // K-tile depth (bf16); 8 K-iterations
#define NBP 392   // padded partial stride (NB=391)
#define CBPR 7    // compress blocks per row (7*4 waves*2048 cols = 57344 >= 50000)
#define CBLKS (CBPR * 512)   // 3584 compress-role blocks

typedef __attribute__((ext_vector_type(8))) short short8;
typedef __attribute__((ext_vector_type(4))) float floatx4;
typedef __attribute__((ext_vector_type(4))) int intx4;
typedef unsigned long long u64;

__device__ __forceinline__ unsigned short f2bf(float f) {
    unsigned int u = __float_as_uint(f);
    u += 0x7FFFu + ((u >> 16) & 1u);   // round-to-nearest-even
    return (unsigned short)(u >> 16);
}

// async global->LDS 16B: lane l's 16B lands at ldsbase + l*16 (wave-uniform base)
__device__ __forceinline__ void gload16(const void* g, void* lds) {
    __builtin_amdgcn_global_load_lds(
        (const __attribute__((address_space(1))) unsigned int*)g,
        (__attribute__((address_space(3))) unsigned int*)lds, 16, 0, 0);
}

// ---- kernel 1: fused label-compress + norms/bf16-convert/loadedmask (R13-exact) -----
// NT loads on read-once streams (labels, V/T): 263.2 -> 254.6 (R13 win, kept).
__global__ __launch_bounds__(256) void prep_compress(
    const float* __restrict__ V, const float* __restrict__ T,
    const int* __restrict__ label, const int* __restrict__ ids,
    u64* __restrict__ loadedmask, u64* __restrict__ posmask,
    unsigned short* __restrict__ Vb, unsigned short* __restrict__ Tb,
    float* __restrict__ gaccum, unsigned int* __restrict__ gcount,
    int B, int C, int n_loaded, int WPR) {
    const int bid = blockIdx.x;
    const int tid = threadIdx.x;
    const int lane = tid & 63;

    if (bid < CBLKS) {   // ---- compress role: 102 MB label stream -> 3.2 MB raw posmask
        int row = bid / CBPR;
        int sub = bid - row * CBPR;
        int wl  = tid >> 6;
        int w0col = (sub * 4 + wl) * 2048;     // this wave's 2048-col window
        if (w0col >= C) return;
        const int* lp = label + (size_t)row * C;
        intx4 lo[4], hi[4];
        #pragma unroll
        for (int r = 0; r < 4; ++r) {          // 8 x 16B nt loads in flight
            int c0 = w0col + r * 512 + lane * 8;
            if (c0 < C) {                      // C%8==0: full 8-col chunk valid
                lo[r] = __builtin_nontemporal_load((const intx4*)(lp + c0));
                hi[r] = __builtin_nontemporal_load((const intx4*)(lp + c0 + 4));
            } else {
                lo[r] = (intx4)0;
                hi[r] = (intx4)0;
            }
        }
        #pragma unroll
        for (int r = 0; r < 4; ++r) {
            unsigned int by =
                (lo[r][0] ? 1u : 0u) | (lo[r][1] ? 2u : 0u) |
                (lo[r][2] ? 4u : 0u) | (lo[r][3] ? 8u : 0u) |
                (hi[r][0] ? 16u : 0u) | (hi[r][1] ? 32u : 0u) |
                (hi[r][2] ? 64u : 0u) | (hi[r][3] ? 128u : 0u);
            u64 wv = (u64)by << (8 * (lane & 7));
            wv |= __shfl_xor(wv, 1);           // OR-butterfly across 8-lane group
            wv |= __shfl_xor(wv, 2);
            wv |= __shfl_xor(wv, 4);
            if ((lane & 7) == 0) {
                int wc = ((w0col + r * 512) >> 6) + (lane >> 3);
                if (wc < WPR) posmask[(size_t)row * WPR + wc] = wv;
            }
        }
        return;
    }

    // ---- prep role: loadedmask (binary search over sorted ids) + normalize -> bf16
    int ptid = (bid - CBLKS) * 256 + tid;
    if (ptid == 0) { *gcount = 0u; *gaccum = 0.f; }   // zero reduce scratch each call
    if (ptid < WPR) {
        int base = ptid << 6;
        int lo = 0, hi = n_loaded;
        while (lo < hi) { int mid = (lo + hi) >> 1; if (ids[mid] < base) lo = mid + 1; else hi = mid; }
        u64 m = 0;
        for (int i = lo; i < n_loaded; ++i) {
            int v = ids[i]; if (v >= base + 64) break;
            m |= 1ull << (v - base);
        }
        loadedmask[ptid] = m;
    }
    int wave = ptid >> 6;
    if (wave >= B + C) return;   // whole wave uniform
    bool isV = wave < B;
    const float* src = isV ? (V + (size_t)wave * D_DIM)
                           : (T + (size_t)(wave - B) * D_DIM);
    floatx4 x = __builtin_nontemporal_load(((const floatx4*)src) + lane);
    float ss = x[0] * x[0] + x[1] * x[1] + x[2] * x[2] + x[3] * x[3];
    #pragma unroll
    for (int off = 32; off > 0; off >>= 1) ss += __shfl_xor(ss, off);
    float nrm = sqrtf(ss);
    float s = isV ? (1.0f / nrm) : (1.0f / (1e-6f + nrm));   // eps on text norms only
    ushort4 o;
    o.x = f2bf(x[0] * s); o.y = f2bf(x[1] * s);
    o.z = f2bf(x[2] * s); o.w = f2bf(x[3] * s);
    unsigned short* dst = isV ? (Vb + (size_t)wave * D_DIM)
                              : (Tb + (size_t)(wave - B) * D_DIM);
    ((ushort4*)dst)[lane] = o;   // cached store: Vb/Tb are re-read by gemm
}

// ---- kernel 2 (R14): R13 gemm + XCD-chunked bijective block swizzle (guide T1) ------
// R13 counters: FETCH 54 MB vs ~28 MB ideal = Tb fetched ~2x. Cause: m-fastest grid
// round-robins the 4 same-Tb blocks onto 4 DIFFERENT XCDs (private L2s) -> duplicate
// fills + L3-latency staging. Swizzle (bijective, ERRATA #11 form): xcd = id&7 gets a
// CONTIGUOUS wgid chunk, so same-n groups share one XCD's L2.
__global__ __launch_bounds__(256) void gemm_fused(
    const unsigned short* __restrict__ Vb, const unsigned short* __restrict__ Tb,
    const u64* __restrict__ posmask, const u64* __restrict__ loadedmask,
    float* __restrict__ denomP, float* __restrict__ posP, int C, int WPR) {
    __shared__ unsigned short As[2][TM * BK];   // 2 x 8 KB double buffer
    __shared__ unsigned short Bs[2][TN * BK];   // 2 x 8 KB
    __shared__ float sDen[TM], sPos[TM];

    const int tid  = threadIdx.x;
    const int lane = tid & 63;
    const int w    = tid >> 6;

    // bijective XCD-chunk swizzle: id%8 = XCD (dispatch round-robin); each XCD gets a
    // contiguous range of wgid. nwg = 1564: q=195, r=4.
    const int nwg  = gridDim.x;
    const int id   = blockIdx.x;
    const int q    = nwg >> 3, r = nwg & 7;
    const int xcd  = id & 7, slot = id >> 3;
    const int wgid = (xcd < r) ? xcd * (q + 1) + slot
                               : r * (q + 1) + (xcd - r) * q + slot;
    const int m0 = (wgid & 3) * TM;     // m fastest within the chunk
    const int nb = wgid >> 2;           // n-block index
    const int n0 = nb * TN;

    if (tid < TM) { sDen[tid] = 0.f; sPos[tid] = 0.f; }

    // ---- async-staging addresses: wave w covers tile rows [w*32, w*32+32)
    const int sra = lane >> 2;          // row within 16-row group
    const int kc  = (lane & 3) * 8;     // 16B k-chunk
    int ga  = m0 + w * 32 + sra;
    int gb0 = n0 + w * 32 + sra;
    int gb1 = gb0 + 16;
    if (gb0 >= C) gb0 = C - 1;          // OOB rows: valid address, masked in epilogue
    if (gb1 >= C) gb1 = C - 1;
    const unsigned short* gA0 = Vb + (size_t)ga * D_DIM + kc;
    const unsigned short* gA1 = gA0 + (size_t)16 * D_DIM;
    const unsigned short* gB0 = Tb + (size_t)gb0 * D_DIM + kc;
    const unsigned short* gB1 = Tb + (size_t)gb1 * D_DIM + kc;
    const int lofsA = w * 32 * BK;      // wave-uniform LDS offsets (elements)
    const int lofsB = w * 32 * BK;

    // ---- compute mapping: 2x2 waves, each 64x64 via 4x4 frags of 16x16x32
    const int wm = (w >> 1) * 64;
    const int wn = (w & 1) * 64;
    const int fr = lane & 15;
    const int quad = lane >> 4;

    floatx4 acc[4][4];
    #pragma unroll
    for (int mi = 0; mi < 4; mi++)
        #pragma unroll
        for (int ni = 0; ni < 4; ni++) acc[mi][ni] = (floatx4)0.f;

    // prologue: stage tile 0 into buffer 0, drain, barrier
    gload16(gA0, &As[0][lofsA]);
    gload16(gA1, &As[0][lofsA + 16 * BK]);
    gload16(gB0, &Bs[0][lofsB]);
    gload16(gB1, &Bs[0][lofsB + 16 * BK]);
    __syncthreads();

    #pragma unroll
    for (int kt = 0; kt < D_DIM / BK; ++kt) {
        const int cur = kt & 1;          // compile-time under full unroll
        if (kt < D_DIM / BK - 1) {       // stage NEXT tile into the other buffer
            const int kb = (kt + 1) * BK;
            gload16(gA0 + kb, &As[cur ^ 1][lofsA]);
            gload16(gA1 + kb, &As[cur ^ 1][lofsA + 16 * BK]);
            gload16(gB0 + kb, &Bs[cur ^ 1][lofsB]);
            gload16(gB1 + kb, &Bs[cur ^ 1][lofsB + 16 * BK]);
        }
        short8 af[4], bf[4];
        #pragma unroll
        for (int mi = 0; mi < 4; mi++)
            af[mi] = *(const short8*)&As[cur][(wm + mi * 16 + fr) * BK + quad * 8];
        #pragma unroll
        for (int ni = 0; ni < 4; ni++)
            bf[ni] = *(const short8*)&Bs[cur][(wn + ni * 16 + fr) * BK + quad * 8];
        #pragma unroll
        for (int mi = 0; mi < 4; mi++)
            #pragma unroll
            for (int ni = 0; ni < 4; ni++)
                acc[mi][ni] = __builtin_amdgcn_mfma_f32_16x16x32_bf16(
                    af[mi], bf[ni], acc[mi][ni], 0, 0, 0);
        __syncthreads();                 // drains this step's stage; swap point
    }

    // ---- epilogue: D layout row = quad*4 + reg, col = lane&15 per 16x16 frag.
    const int wcol = (n0 + wn) >> 6;          // this wave's 64-col mask word
    const u64 loadedw = loadedmask[wcol];
    #pragma unroll
    for (int mi = 0; mi < 4; mi++) {
        #pragma unroll
        for (int i = 0; i < 4; i++) {
            const int mloc = wm + mi * 16 + quad * 4 + i;
            const u64 praw = posmask[(size_t)(m0 + mloc) * WPR + wcol];  // L2/L3-hit
            const u64 posw = praw & loadedw;
            const u64 negw = loadedw & ~praw;
            float den = 0.f, pos = 0.f;
            #pragma unroll
            for (int ni = 0; ni < 4; ni++) {
                const float s = acc[mi][ni][i];
                const int bit = ni * 16 + fr;
                if ((negw >> bit) & 1) den += __expf(s);
                if ((posw >> bit) & 1) pos += s;
            }
            #pragma unroll
            for (int off = 8; off >= 1; off >>= 1) {   // reduce 16-lane quad row
                den += __shfl_xor(den, off);
                pos += __shfl_xor(pos, off);
            }
            if (fr == 0) {
                if (den != 0.f) atomicAdd(&sDen[mloc], den);
                if (pos != 0.f) atomicAdd(&sPos[mloc], pos);
            }
        }
    }
    __syncthreads();
    if (tid < TM) {   // row-major partials: [row][n-block] for coalesced reduce
        denomP[(size_t)(m0 + tid) * NBP + nb] = sDen[tid];
        posP[(size_t)(m0 + tid) * NBP + nb]   = sPos[tid];
    }
}

// ---- kernel 3: reduce rows + last-block computes the final mean (R5-exact) ----------
__global__ void reduce_rows(const float* __restrict__ denomP, const float* __restrict__ posP,
                            const u64* __restrict__ posmask, const u64* __restrict__ loadedmask,
                            float* __restrict__ gaccum, unsigned int* __restrict__ gcount,
                            float* __restrict__ out, int B, int NB, int WPR) {
    __shared__ float bsum[4];
    int wv   = threadIdx.x >> 6;
    int row  = blockIdx.x * 4 + wv;
    int lane = threadIdx.x & 63;
    float den = 0.f, pos = 0.f;
    int cnt = 0;
    if (row < B) {
        for (int bn = lane; bn < NB; bn += 64) {   // contiguous within row: coalesced
            den += denomP[(size_t)row * NBP + bn];
            pos += posP[(size_t)row * NBP + bn];
        }
        for (int j = lane; j < WPR; j += 64)
            cnt += __popcll(posmask[(size_t)row * WPR + j] & loadedmask[j]);
        #pragma unroll
        for (int off = 32; off > 0; off >>= 1) {
            den += __shfl_xor(den, off);
            pos += __shfl_xor(pos, off);
            cnt += __shfl_xor(cnt, off);
        }
    }
    if (lane == 0) bsum[wv] = (row < B) ? (logf(den) - pos / (float)cnt) : 0.f;
    __syncthreads();
    if (threadIdx.x == 0) {
        float s = bsum[0] + bsum[1] + bsum[2] + bsum[3];
        atomicAdd(gaccum, s);            // 128 ops total: contention negligible
        __threadfence();
        unsigned int old = atomicAdd(gcount, 1u);
        if (old == gridDim.x - 1) {      // last block: all adds complete & visible
            float tot = atomicAdd(gaccum, 0.0f);   // atomic read-back
            out[0] = tot / (float)B;
        }
    }
}

extern "C" void kernel_launch(void* const* d_in, const int* in_sizes, int n_in,
                              void* d_out, int out_size, void* d_ws, size_t ws_size,
                              hipStream_t stream) {
    const float* V     = (const float*)d_in[0];
    const float* T     = (const float*)d_in[1];
    const int*   label = (const int*)d_in[2];
    const int*   ids   = (const int*)d_in[3];
    int B = in_sizes[0] / D_DIM;   // 512
    int C = in_sizes[1] / D_DIM;   // 50000
    int n_loaded = in_sizes[3];    // 40000
    int WPR = (C + 63) >> 6;       // mask words per row (782)
    int NB  = (C + TN - 1) / TN;   // n-blocks (391)

    // ws layout (bytes):
    //   0        : gaccum [1 f], gcount [1 u32]     (pad to 2048)
    //   2048     : loadedmask [782 u64]             (ends 8304; pad to 8320)
    //   8320     : posmask [512*782 u64]            (3,203,072 -> ends 3,211,392)
    //   3211392  : Vb [512*256 bf16]                (262,144 -> ends 3,473,536)
    //   3473536  : Tb [50000*256 bf16]              (25.6 MB -> ends 29,073,536)
    //   29073536 : denomP [512*NBP f]               (802,816 -> ends 29,876,352)
    //   29876352 : posP                             (ends 30,679,168)
    char* ws = (char*)d_ws;
    float*        gaccum = (float*)(ws + 0);
    unsigned int* gcount = (unsigned int*)(ws + 8);
    u64*   loadedmask = (u64*)(ws + 2048);
    u64*   posmask    = (u64*)(ws + 8320);
    unsigned short* Vb = (unsigned short*)(ws + 3211392);
    unsigned short* Tb = (unsigned short*)(ws + 3473536);
    float* denomP  = (float*)(ws + 29073536);
    float* posP    = (float*)(ws + 29876352);

    int prep_blocks = ((B + C) * 64 + 255) / 256;    // 12628
    prep_compress<<<CBLKS + prep_blocks, 256, 0, stream>>>(
        V, T, label, ids, loadedmask, posmask, Vb, Tb, gaccum, gcount,
        B, C, n_loaded, WPR);

    int gemm_blocks = (B / TM) * NB;   // 1564; 1D grid for the XCD swizzle
    gemm_fused<<<gemm_blocks, 256, 0, stream>>>(Vb, Tb, posmask, loadedmask,
                                                denomP, posP, C, WPR);

    reduce_rows<<<(B + 3) / 4, 256, 0, stream>>>(denomP, posP, posmask, loadedmask,
                                                 gaccum, gcount, (float*)d_out, B, NB, WPR);
}